// Round 2
// baseline (340.747 us; speedup 1.0000x reference)
//
#include <hip/hip_runtime.h>
#include <math.h>

constexpr int L = 256;
constexpr float EPS = 1e-6f;
constexpr int NT = 1024;       // threads per block
constexpr int NW = NT / 64;    // 16 waves per block

__device__ inline float wave_sum(float v) {
#pragma unroll
    for (int off = 32; off > 0; off >>= 1) v += __shfl_down(v, off, 64);
    return v;
}

// One block per sample. 1024 threads -> 16 waves/block, 2 blocks/CU = 32 waves/CU.
__global__ __launch_bounds__(NT, 8) void per_sample_kernel(
    const float* __restrict__ Yp, const float* __restrict__ Yg,
    float* __restrict__ ratios) {
    const int b = blockIdx.x;
    const int t = threadIdx.x;
    const float* yp = Yp + (size_t)b * L * L;
    const float* yg = Yg + (size_t)b * L * L;
    const float4* yp4 = (const float4*)yp;
    const float4* yg4 = (const float4*)yg;

    __shared__ unsigned rowmask[8], colmask[8];
    __shared__ float part1[NW], part2[NW];
    __shared__ int s_anyg;
    __shared__ float s_sum_p, s_sum_pg;
    __shared__ int s_box[4];   // col_lo, col_hi, row_lo, row_hi
    __shared__ float s_par[4]; // gt0, gt1, inv_xr, inv_yr
    __shared__ int s_empty;

    if (t < 8) { rowmask[t] = 0u; colmask[t] = 0u; }
    if (t == 0) s_anyg = 0;
    __syncthreads();

    // Pass 1: full read of Yp and Yg. 16384 float4 / 1024 thr = 16 per thread.
    // 2-deep staging of (p,g) pairs for in-flight load ILP.
    float sum_p = 0.f, sum_pg = 0.f;
    int anyg = 0;
#pragma unroll
    for (int kk = 0; kk < 8; ++kk) {
        float4 p0, p1, g0, g1;
        const int j0 = t + ((kk * 2 + 0) << 10);
        const int j1 = t + ((kk * 2 + 1) << 10);
        p0 = yp4[j0]; g0 = yg4[j0];
        p1 = yp4[j1]; g1 = yg4[j1];
#pragma unroll
        for (int u = 0; u < 2; ++u) {
            const float4 p = u ? p1 : p0;
            const float4 g = u ? g1 : g0;
            const int j = u ? j1 : j0;
            sum_p  += (p.x + p.y) + (p.z + p.w);
            sum_pg += p.x * g.x + p.y * g.y + p.z * g.z + p.w * g.w;
            anyg |= (g.x > 0.f) | (g.y > 0.f) | (g.z > 0.f) | (g.w > 0.f);
            const bool bx = p.x > 0.5f, by = p.y > 0.5f,
                       bz = p.z > 0.5f, bw = p.w > 0.5f;
            if (bx | by | bz | bw) {      // rare: only blob pixels exceed 0.5
                const int row = j >> 6;   // flat float idx = 4j; row = 4j>>8
                atomicOr(&rowmask[row >> 5], 1u << (row & 31));
                const int c0 = (j << 2) & 255; // first col of this float4
                const unsigned bits =
                    ((unsigned)bx | ((unsigned)by << 1) | ((unsigned)bz << 2) |
                     ((unsigned)bw << 3)) << (c0 & 31);
                atomicOr(&colmask[c0 >> 5], bits);
            }
        }
    }
    const int wave = t >> 6, lane = t & 63;
    if (__any(anyg) && lane == 0) atomicOr(&s_anyg, 1);  // 1 atomic per wave

    float w1 = wave_sum(sum_p);
    float w2 = wave_sum(sum_pg);
    if (lane == 0) { part1[wave] = w1; part2[wave] = w2; }
    __syncthreads();

    if (t == 0) {
        float sp = 0.f, spg = 0.f;
        for (int i = 0; i < NW; ++i) { sp += part1[i]; spg += part2[i]; }
        s_sum_p = sp; s_sum_pg = spg;
        // Box bounds from 256-bit masks.
        int first_r = 0, last_r = 0, first_c = 0, last_c = 0;
        bool any_r = false, any_c = false;
        for (int i = 0; i < 8; ++i) {
            unsigned w = rowmask[i];
            if (w) {
                if (!any_r) { first_r = i * 32 + __builtin_ffs((int)w) - 1; any_r = true; }
                last_r = i * 32 + 31 - __builtin_clz(w);
            }
            unsigned wc = colmask[i];
            if (wc) {
                if (!any_c) { first_c = i * 32 + __builtin_ffs((int)wc) - 1; any_c = true; }
                last_c = i * 32 + 31 - __builtin_clz(wc);
            }
        }
        // Faithful to reference (incl. the row/col swap and floor division).
        const int left  = any_r ? first_r : 0;
        const int right = any_r ? (L - 1 - last_r) : 0;
        const int up    = any_c ? first_c : 0;
        const int down  = any_c ? (L - 1 - last_c) : 0;
        const int x_r = (right - left) >> 1;  // arith shift = floor div (Python //)
        const int y_r = (down - up) >> 1;
        const float gt0 = (float)(left + x_r);  // compared against COLUMN coord
        const float gt1 = (float)(up + y_r);    // compared against ROW coord
        if (s_anyg || x_r == 0 || y_r == 0) {
            s_empty = 1;  // gt branch taken, or mask provably empty (inf/nan)
        } else {
            s_empty = 0;
            s_par[0] = gt0; s_par[1] = gt1;
            s_par[2] = 1.f / (float)x_r; s_par[3] = 1.f / (float)y_r;
            // mask needs d0^4+d1^4 < ln(10)*4/9 => |d0| <= 1.0059 ; pad a bit
            const float mx = fabsf((float)x_r) * 1.02f + 1.f;
            const float my = fabsf((float)y_r) * 1.02f + 1.f;
            s_box[0] = max(0, (int)floorf(gt0 - mx));
            s_box[1] = min(L - 1, (int)ceilf(gt0 + mx));
            s_box[2] = max(0, (int)floorf(gt1 - my));
            s_box[3] = min(L - 1, (int)ceilf(gt1 + my));
        }
    }
    __syncthreads();

    // Pass 2 (tiny): sum Yp over generated mask inside the bounding box.
    float pos_gen = 0.f;
    if (!s_empty) {
        const int cl = s_box[0], ch = s_box[1], rl = s_box[2], rh = s_box[3];
        const int W = ch - cl + 1, H = rh - rl + 1;
        const float gt0 = s_par[0], gt1 = s_par[1];
        const float inv_xr = s_par[2], inv_yr = s_par[3];
        for (int idx = t; idx < W * H; idx += NT) {
            const int r = rl + idx / W;
            const int c = cl + idx % W;
            float d0 = ((float)c - gt0) * inv_xr;
            float d1 = ((float)r - gt1) * inv_yr;
            d0 *= d0; d0 *= d0;   // d0^4
            d1 *= d1; d1 *= d1;   // d1^4
            const float h = __expf(-2.25f * (d0 + d1));  // exp(-h' / (2/3)^2)
            if (h > 0.1f) pos_gen += yp[r * L + c];
        }
    }
    float w3 = wave_sum(pos_gen);
    if (lane == 0) part1[wave] = w3;
    __syncthreads();
    if (t == 0) {
        float pg = 0.f;
        for (int i = 0; i < NW; ++i) pg += part1[i];
        const float positive = s_anyg ? s_sum_pg : pg;
        ratios[b] = (s_sum_p - positive) / (positive + EPS);
    }
}

__global__ __launch_bounds__(256) void finalize_kernel(
    const float* __restrict__ ratios, float* __restrict__ out, int B) {
    float v = 0.f;
    for (int i = threadIdx.x; i < B; i += 256) v += ratios[i];
    v = wave_sum(v);
    __shared__ float part[4];
    const int wave = threadIdx.x >> 6, lane = threadIdx.x & 63;
    if (lane == 0) part[wave] = v;
    __syncthreads();
    if (threadIdx.x == 0) {
        const float total = part[0] + part[1] + part[2] + part[3];
        out[0] = (total == 0.f) ? 0.f : logf(total) / (float)B;
    }
}

extern "C" void kernel_launch(void* const* d_in, const int* in_sizes, int n_in,
                              void* d_out, int out_size, void* d_ws, size_t ws_size,
                              hipStream_t stream) {
    const float* Yp = (const float*)d_in[0];
    const float* Yg = (const float*)d_in[1];
    const int B = in_sizes[0] / (L * L);
    float* ratios = (float*)d_ws;   // B floats of scratch
    per_sample_kernel<<<B, NT, 0, stream>>>(Yp, Yg, ratios);
    finalize_kernel<<<1, 256, 0, stream>>>(ratios, (float*)d_out, B);
}

// Round 3
// 285.232 us; speedup vs baseline: 1.1946x; 1.1946x over previous
//
#include <hip/hip_runtime.h>
#include <math.h>

constexpr int L = 256;
constexpr float EPS = 1e-6f;
constexpr int SPLIT = 4;        // blocks per sample in pass 1
constexpr int REC_WORDS = 20;   // per-sample record (u32 words), padded

// Record layout (u32 words): [0]=sum_p(float) [1]=sum_pg(float) [2]=anyg
// [3..10]=rowmask[8] [11..18]=colmask[8] [19]=pad

__device__ inline float wave_sum(float v) {
#pragma unroll
    for (int off = 32; off > 0; off >>= 1) v += __shfl_down(v, off, 64);
    return v;
}

__global__ __launch_bounds__(256) void zero_kernel(unsigned* __restrict__ w, int n) {
    const int i = blockIdx.x * 256 + threadIdx.x;
    if (i < n) w[i] = 0u;
}

// Pass 1: grid = B*SPLIT blocks of 256 threads. Each block streams a
// contiguous quarter (64 rows) of one sample; merges into the sample record
// with device-scope atomics.
__global__ __launch_bounds__(256) void pass1_kernel(
    const float* __restrict__ Yp, const float* __restrict__ Yg,
    unsigned* __restrict__ recs) {
    const int blk = blockIdx.x;
    const int b = blk >> 2;       // sample
    const int s = blk & 3;        // split (64 rows each)
    const int t = threadIdx.x;
    const float4* yp4 = (const float4*)(Yp + (size_t)b * L * L) + s * 4096;
    const float4* yg4 = (const float4*)(Yg + (size_t)b * L * L) + s * 4096;
    unsigned* rec = recs + b * REC_WORDS;

    __shared__ unsigned rowmask[8], colmask[8];
    __shared__ float part1[4], part2[4];
    if (t < 8) { rowmask[t] = 0u; colmask[t] = 0u; }
    __syncthreads();

    float sum_p = 0.f, sum_pg = 0.f;
    int anyg = 0;
#pragma unroll 4
    for (int k = 0; k < 16; ++k) {
        const int j = t + (k << 8);           // local float4 idx in [0,4096)
        const float4 p = yp4[j];
        const float4 g = yg4[j];
        sum_p  += (p.x + p.y) + (p.z + p.w);
        sum_pg += p.x * g.x + p.y * g.y + p.z * g.z + p.w * g.w;
        anyg |= (g.x > 0.f) | (g.y > 0.f) | (g.z > 0.f) | (g.w > 0.f);
        const bool bx = p.x > 0.5f, by = p.y > 0.5f,
                   bz = p.z > 0.5f, bw = p.w > 0.5f;
        if (bx | by | bz | bw) {              // rare: only blob pixels
            const int gj = s * 4096 + j;      // global float4 idx in sample
            const int row = gj >> 6;          // 64 float4 per row
            atomicOr(&rowmask[row >> 5], 1u << (row & 31));
            const int c0 = (gj << 2) & 255;   // first col of this float4
            const unsigned bits =
                ((unsigned)bx | ((unsigned)by << 1) | ((unsigned)bz << 2) |
                 ((unsigned)bw << 3)) << (c0 & 31);
            atomicOr(&colmask[c0 >> 5], bits);
        }
    }
    const int wave = t >> 6, lane = t & 63;
    const int wany = __any(anyg);
    if (lane == 0 && wany) atomicOr(&rec[2], 1u);

    float w1 = wave_sum(sum_p);
    float w2 = wave_sum(sum_pg);
    if (lane == 0) { part1[wave] = w1; part2[wave] = w2; }
    __syncthreads();

    if (t == 0) {
        atomicAdd((float*)&rec[0], part1[0] + part1[1] + part1[2] + part1[3]);
        atomicAdd((float*)&rec[1], part2[0] + part2[1] + part2[2] + part2[3]);
    } else if (t >= 32 && t < 40) {
        const unsigned m = rowmask[t - 32];
        if (m) atomicOr(&rec[3 + (t - 32)], m);
    } else if (t >= 40 && t < 48) {
        const unsigned m = colmask[t - 40];
        if (m) atomicOr(&rec[11 + (t - 40)], m);
    }
}

// Pass 2: one wave per sample. Box math (redundantly on all lanes) + tiny
// mask-box sum over Yp + ratio.
__global__ __launch_bounds__(64) void pass2_kernel(
    const float* __restrict__ Yp, const unsigned* __restrict__ recs,
    float* __restrict__ ratios) {
    const int b = blockIdx.x;
    const int lane = threadIdx.x;
    const unsigned* rec = recs + b * REC_WORDS;
    const float* yp = Yp + (size_t)b * L * L;

    const float sum_p  = ((const float*)rec)[0];
    const float sum_pg = ((const float*)rec)[1];
    const unsigned anyg = rec[2];

    // Box bounds from the 256-bit masks (identical on every lane).
    int first_r = 0, last_r = 0, first_c = 0, last_c = 0;
    bool any_r = false, any_c = false;
#pragma unroll
    for (int i = 0; i < 8; ++i) {
        const unsigned wr = rec[3 + i];
        if (wr) {
            if (!any_r) { first_r = i * 32 + __builtin_ffs((int)wr) - 1; any_r = true; }
            last_r = i * 32 + 31 - __builtin_clz(wr);
        }
        const unsigned wc = rec[11 + i];
        if (wc) {
            if (!any_c) { first_c = i * 32 + __builtin_ffs((int)wc) - 1; any_c = true; }
            last_c = i * 32 + 31 - __builtin_clz(wc);
        }
    }
    // Faithful to reference (incl. the row/col swap and Python floor division).
    const int left  = any_r ? first_r : 0;
    const int right = any_r ? (L - 1 - last_r) : 0;
    const int up    = any_c ? first_c : 0;
    const int down  = any_c ? (L - 1 - last_c) : 0;
    const int x_r = (right - left) >> 1;   // arithmetic shift = floor div
    const int y_r = (down - up) >> 1;
    const float gt0 = (float)(left + x_r); // compared against COLUMN coord
    const float gt1 = (float)(up + y_r);   // compared against ROW coord

    float positive;
    if (anyg) {
        positive = sum_pg;
    } else if (x_r == 0 || y_r == 0) {
        positive = 0.f;  // generated mask provably empty (inf/nan -> h not > 0.1)
    } else {
        const float inv_xr = 1.f / (float)x_r;
        const float inv_yr = 1.f / (float)y_r;
        // mask needs d0^4+d1^4 < ln(10)*4/9 => |d0| <= 1.0059 ; pad a bit
        const float mx = fabsf((float)x_r) * 1.02f + 1.f;
        const float my = fabsf((float)y_r) * 1.02f + 1.f;
        const int cl = max(0, (int)floorf(gt0 - mx));
        const int ch = min(L - 1, (int)ceilf(gt0 + mx));
        const int rl = max(0, (int)floorf(gt1 - my));
        const int rh = min(L - 1, (int)ceilf(gt1 + my));
        const int W = ch - cl + 1, H = rh - rl + 1;
        float pos = 0.f;
        for (int idx = lane; idx < W * H; idx += 64) {
            const int r = rl + idx / W;
            const int c = cl + idx % W;
            float d0 = ((float)c - gt0) * inv_xr;
            float d1 = ((float)r - gt1) * inv_yr;
            d0 *= d0; d0 *= d0;    // d0^4
            d1 *= d1; d1 *= d1;    // d1^4
            const float h = __expf(-2.25f * (d0 + d1));  // exp(-h'/(2/3)^2)
            if (h > 0.1f) pos += yp[r * L + c];
        }
        positive = wave_sum(pos);  // valid in lane 0
    }
    if (lane == 0) ratios[b] = (sum_p - positive) / (positive + EPS);
}

__global__ __launch_bounds__(256) void finalize_kernel(
    const float* __restrict__ ratios, float* __restrict__ out, int B) {
    float v = 0.f;
    for (int i = threadIdx.x; i < B; i += 256) v += ratios[i];
    v = wave_sum(v);
    __shared__ float part[4];
    const int wave = threadIdx.x >> 6, lane = threadIdx.x & 63;
    if (lane == 0) part[wave] = v;
    __syncthreads();
    if (threadIdx.x == 0) {
        const float total = part[0] + part[1] + part[2] + part[3];
        out[0] = (total == 0.f) ? 0.f : logf(total) / (float)B;
    }
}

extern "C" void kernel_launch(void* const* d_in, const int* in_sizes, int n_in,
                              void* d_out, int out_size, void* d_ws, size_t ws_size,
                              hipStream_t stream) {
    const float* Yp = (const float*)d_in[0];
    const float* Yg = (const float*)d_in[1];
    const int B = in_sizes[0] / (L * L);
    unsigned* recs = (unsigned*)d_ws;                    // B*REC_WORDS u32
    float* ratios = (float*)((char*)d_ws + (size_t)B * REC_WORDS * 4);
    const int nz = B * REC_WORDS;
    zero_kernel<<<(nz + 255) / 256, 256, 0, stream>>>(recs, nz);
    pass1_kernel<<<B * SPLIT, 256, 0, stream>>>(Yp, Yg, recs);
    pass2_kernel<<<B, 64, 0, stream>>>(Yp, recs, ratios);
    finalize_kernel<<<1, 256, 0, stream>>>(ratios, (float*)d_out, B);
}

// Round 5
// 279.156 us; speedup vs baseline: 1.2206x; 1.0218x over previous
//
#include <hip/hip_runtime.h>
#include <math.h>

constexpr int L = 256;
constexpr float EPS = 1e-6f;
constexpr int SPLIT = 8;      // blocks per sample in pass 1 (32 rows each)
constexpr int REC_WORDS = 8;  // per-sample record (u32 words)

// Record layout (u32 words):
// [0]=sum_p(f32,add) [1]=sum_pg(f32,add) [2]=anyg(or)
// [3]=minr(i32,min,init INT_MAX) [4]=maxr(i32,max,init -1)
// [5]=minc(i32,min,init INT_MAX) [6]=maxc(i32,max,init -1) [7]=pad

__device__ inline float wave_sum(float v) {
#pragma unroll
    for (int off = 32; off > 0; off >>= 1) v += __shfl_down(v, off, 64);
    return v;
}
__device__ inline int wave_min(int v) {
#pragma unroll
    for (int off = 32; off > 0; off >>= 1) v = min(v, __shfl_down(v, off, 64));
    return v;
}
__device__ inline int wave_max(int v) {
#pragma unroll
    for (int off = 32; off > 0; off >>= 1) v = max(v, __shfl_down(v, off, 64));
    return v;
}

__global__ __launch_bounds__(256) void init_kernel(unsigned* __restrict__ w, int n) {
    const int i = blockIdx.x * 256 + threadIdx.x;
    if (i < n) {
        const int k = i & 7;
        unsigned v = 0u;
        if (k == 3 || k == 5) v = 0x7FFFFFFFu;       // min sentinels
        else if (k == 4 || k == 6) v = 0xFFFFFFFFu;  // max sentinels (-1)
        w[i] = v;
    }
}

// Pass 1: grid = B*SPLIT blocks of 256 threads; each block streams 32 rows of
// one sample. Branch-free, atomic-free inner loop; all 16 loads issued before
// first use (register staging) for max memory-level parallelism.
__global__ __launch_bounds__(256) void pass1_kernel(
    const float* __restrict__ Yp, const float* __restrict__ Yg,
    unsigned* __restrict__ recs) {
    const int b = blockIdx.x >> 3;   // sample
    const int s = blockIdx.x & 7;    // 32-row slice
    const int t = threadIdx.x;
    const float4* yp4 = (const float4*)(Yp + (size_t)b * L * L) + s * 2048;
    const float4* yg4 = (const float4*)(Yg + (size_t)b * L * L) + s * 2048;
    unsigned* rec = recs + b * REC_WORDS;

    // Load everything first: 16 independent float4 loads in flight.
    float4 P[8], G[8];
#pragma unroll
    for (int k = 0; k < 8; ++k) P[k] = yp4[t + (k << 8)];
#pragma unroll
    for (int k = 0; k < 8; ++k) G[k] = yg4[t + (k << 8)];

    // Per-thread geometry is data-independent:
    //   row(k) = s*32 + (t>>6) + 4k ; cols = c0..c0+3 with c0 = (t&63)*4
    const int rowbase = s * 32 + (t >> 6);
    const int c0 = (t & 63) << 2;

    float sum_p = 0.f, sum_pg = 0.f;
    int anyg = 0;
    unsigned rowbits = 0u;                   // bit k: any pixel >0.5 at row(k)
    unsigned cb0 = 0, cb1 = 0, cb2 = 0, cb3 = 0;  // per-column presence
#pragma unroll
    for (int k = 0; k < 8; ++k) {
        const float4 p = P[k], g = G[k];
        sum_p  += (p.x + p.y) + (p.z + p.w);
        sum_pg += p.x * g.x + p.y * g.y + p.z * g.z + p.w * g.w;
        anyg |= (g.x > 0.f) | (g.y > 0.f) | (g.z > 0.f) | (g.w > 0.f);
        const unsigned bx = p.x > 0.5f, by = p.y > 0.5f,
                       bz = p.z > 0.5f, bw = p.w > 0.5f;
        rowbits |= (bx | by | bz | bw) << k;
        cb0 |= bx; cb1 |= by; cb2 |= bz; cb3 |= bw;
    }
    // Collapse to per-thread box candidates.
    int minr = 0x7FFFFFFF, maxr = -1, minc = 0x7FFFFFFF, maxc = -1;
    if (rowbits) {
        minr = rowbase + 4 * __builtin_ctz(rowbits);
        maxr = rowbase + 4 * (31 - __builtin_clz(rowbits));
        const unsigned colbits = cb0 | (cb1 << 1) | (cb2 << 2) | (cb3 << 3);
        minc = c0 + __builtin_ctz(colbits);
        maxc = c0 + (31 - __builtin_clz(colbits));
    }

    // Wave reduce, then LDS across 4 waves, then one set of global atomics.
    const int wave = t >> 6, lane = t & 63;
    const float wsp = wave_sum(sum_p);
    const float wspg = wave_sum(sum_pg);
    const int wanyg = __any(anyg);
    const int wminr = wave_min(minr), wmaxr = wave_max(maxr);
    const int wminc = wave_min(minc), wmaxc = wave_max(maxc);

    __shared__ float sh_p[4], sh_pg[4];
    __shared__ int sh_a[4], sh_minr[4], sh_maxr[4], sh_minc[4], sh_maxc[4];
    if (lane == 0) {
        sh_p[wave] = wsp; sh_pg[wave] = wspg; sh_a[wave] = wanyg;
        sh_minr[wave] = wminr; sh_maxr[wave] = wmaxr;
        sh_minc[wave] = wminc; sh_maxc[wave] = wmaxc;
    }
    __syncthreads();
    if (t == 0) {
        float sp = 0.f, spg = 0.f;
        int a = 0, mnr = 0x7FFFFFFF, mxr = -1, mnc = 0x7FFFFFFF, mxc = -1;
#pragma unroll
        for (int i = 0; i < 4; ++i) {
            sp += sh_p[i]; spg += sh_pg[i]; a |= sh_a[i];
            mnr = min(mnr, sh_minr[i]); mxr = max(mxr, sh_maxr[i]);
            mnc = min(mnc, sh_minc[i]); mxc = max(mxc, sh_maxc[i]);
        }
        atomicAdd((float*)&rec[0], sp);
        atomicAdd((float*)&rec[1], spg);
        if (a) atomicOr(&rec[2], 1u);
        if (mxr >= 0) {   // this slice saw blob pixels
            atomicMin((int*)&rec[3], mnr);
            atomicMax((int*)&rec[4], mxr);
            atomicMin((int*)&rec[5], mnc);
            atomicMax((int*)&rec[6], mxc);
        }
    }
}

// Pass 2: one wave per sample. Box math (redundant on all lanes) + tiny
// mask-box sum over Yp + ratio.
__global__ __launch_bounds__(64) void pass2_kernel(
    const float* __restrict__ Yp, const unsigned* __restrict__ recs,
    float* __restrict__ ratios) {
    const int b = blockIdx.x;
    const int lane = threadIdx.x;
    const unsigned* rec = recs + b * REC_WORDS;
    const float* yp = Yp + (size_t)b * L * L;

    const float sum_p  = ((const float*)rec)[0];
    const float sum_pg = ((const float*)rec)[1];
    const unsigned anyg = rec[2];
    const int minr = (int)rec[3], maxr = (int)rec[4];
    const int minc = (int)rec[5], maxc = (int)rec[6];

    // Faithful to reference (incl. the row/col swap and Python floor division).
    const bool any_r = maxr >= 0, any_c = maxc >= 0;
    const int left  = any_r ? minr : 0;
    const int right = any_r ? (L - 1 - maxr) : 0;
    const int up    = any_c ? minc : 0;
    const int down  = any_c ? (L - 1 - maxc) : 0;
    const int x_r = (right - left) >> 1;   // arithmetic shift = floor div
    const int y_r = (down - up) >> 1;
    const float gt0 = (float)(left + x_r); // compared against COLUMN coord
    const float gt1 = (float)(up + y_r);   // compared against ROW coord

    float positive;
    if (anyg) {
        positive = sum_pg;
    } else if (x_r == 0 || y_r == 0) {
        positive = 0.f;  // generated mask provably empty (inf/nan -> h not > 0.1)
    } else {
        const float inv_xr = 1.f / (float)x_r;
        const float inv_yr = 1.f / (float)y_r;
        // mask needs d0^4+d1^4 < ln(10)*4/9 => |d| <= 1.0059 ; pad a bit
        const float mx = fabsf((float)x_r) * 1.02f + 1.f;
        const float my = fabsf((float)y_r) * 1.02f + 1.f;
        const int cl = max(0, (int)floorf(gt0 - mx));
        const int ch = min(L - 1, (int)ceilf(gt0 + mx));
        const int rl = max(0, (int)floorf(gt1 - my));
        const int rh = min(L - 1, (int)ceilf(gt1 + my));
        const int W = ch - cl + 1, H = rh - rl + 1;
        float pos = 0.f;
        for (int idx = lane; idx < W * H; idx += 64) {
            const int r = rl + idx / W;
            const int c = cl + idx % W;
            float d0 = ((float)c - gt0) * inv_xr;
            float d1 = ((float)r - gt1) * inv_yr;
            d0 *= d0; d0 *= d0;    // d0^4
            d1 *= d1; d1 *= d1;    // d1^4
            const float h = __expf(-2.25f * (d0 + d1));  // exp(-h'/(2/3)^2)
            if (h > 0.1f) pos += yp[r * L + c];
        }
        positive = wave_sum(pos);  // valid in lane 0
    }
    if (lane == 0) ratios[b] = (sum_p - positive) / (positive + EPS);
}

__global__ __launch_bounds__(256) void finalize_kernel(
    const float* __restrict__ ratios, float* __restrict__ out, int B) {
    float v = 0.f;
    for (int i = threadIdx.x; i < B; i += 256) v += ratios[i];
    v = wave_sum(v);
    __shared__ float part[4];
    const int wave = threadIdx.x >> 6, lane = threadIdx.x & 63;
    if (lane == 0) part[wave] = v;
    __syncthreads();
    if (threadIdx.x == 0) {
        const float total = part[0] + part[1] + part[2] + part[3];
        out[0] = (total == 0.f) ? 0.f : logf(total) / (float)B;
    }
}

extern "C" void kernel_launch(void* const* d_in, const int* in_sizes, int n_in,
                              void* d_out, int out_size, void* d_ws, size_t ws_size,
                              hipStream_t stream) {
    const float* Yp = (const float*)d_in[0];
    const float* Yg = (const float*)d_in[1];
    const int B = in_sizes[0] / (L * L);
    unsigned* recs = (unsigned*)d_ws;                    // B*REC_WORDS u32
    float* ratios = (float*)((char*)d_ws + (size_t)B * REC_WORDS * 4);
    const int nz = B * REC_WORDS;
    init_kernel<<<(nz + 255) / 256, 256, 0, stream>>>(recs, nz);
    pass1_kernel<<<B * SPLIT, 256, 0, stream>>>(Yp, Yg, recs);
    pass2_kernel<<<B, 64, 0, stream>>>(Yp, recs, ratios);
    finalize_kernel<<<1, 256, 0, stream>>>(ratios, (float*)d_out, B);
}

// Round 6
// 262.744 us; speedup vs baseline: 1.2969x; 1.0625x over previous
//
#include <hip/hip_runtime.h>
#include <math.h>

constexpr int L = 256;
constexpr float EPS = 1e-6f;
constexpr int REC_WORDS = 8;  // per-sample record (u32 words)

// Record layout (u32 words):
// [0]=sum_p(f32,add) [1]=sum_pg(f32,add) [2]=anyg(or)
// [3]=minr(i32,min,init INT_MAX) [4]=maxr(i32,max,init -1)
// [5]=minc(i32,min,init INT_MAX) [6]=maxc(i32,max,init -1) [7]=pad

typedef float f32x4 __attribute__((ext_vector_type(4)));

__device__ inline float wave_sum(float v) {
#pragma unroll
    for (int off = 32; off > 0; off >>= 1) v += __shfl_down(v, off, 64);
    return v;
}
__device__ inline int wave_min(int v) {
#pragma unroll
    for (int off = 32; off > 0; off >>= 1) v = min(v, __shfl_down(v, off, 64));
    return v;
}
__device__ inline int wave_max(int v) {
#pragma unroll
    for (int off = 32; off > 0; off >>= 1) v = max(v, __shfl_down(v, off, 64));
    return v;
}

__global__ __launch_bounds__(256) void init_kernel(unsigned* __restrict__ w, int n) {
    const int i = blockIdx.x * 256 + threadIdx.x;
    if (i < n) {
        const int k = i & 7;
        unsigned v = 0u;
        if (k == 3 || k == 5) v = 0x7FFFFFFFu;       // min sentinels
        else if (k == 4 || k == 6) v = 0xFFFFFFFFu;  // max sentinels (-1)
        w[i] = v;
    }
}

// Pass 1: grid = B*2 blocks of 256 threads. Each block streams a contiguous
// 128-row half of one sample (128 KB per array) as one software-pipelined
// load stream: 4+4 float4 double-buffer, next iteration's loads in flight
// while current is consumed. One drain per block instead of per 64 KB.
__global__ __launch_bounds__(256) void pass1_kernel(
    const float* __restrict__ Yp, const float* __restrict__ Yg,
    unsigned* __restrict__ recs) {
    const int b = blockIdx.x >> 1;   // sample
    const int h = blockIdx.x & 1;    // 128-row half
    const int t = threadIdx.x;
    const f32x4* yp4 = (const f32x4*)(Yp + (size_t)b * L * L) + h * 8192;
    const f32x4* yg4 = (const f32x4*)(Yg + (size_t)b * L * L) + h * 8192;
    unsigned* rec = recs + b * REC_WORDS;

    // Prologue: load iteration 0's 8 float4.
    f32x4 Pc[4], Gc[4], Pn[4], Gn[4];
#pragma unroll
    for (int k = 0; k < 4; ++k) {
        Pc[k] = __builtin_nontemporal_load(yp4 + (k << 8) + t);
        Gc[k] = __builtin_nontemporal_load(yg4 + (k << 8) + t);
    }

    // Per-thread geometry is data-independent:
    //   float4 idx j = it*1024 + k*256 + t  (it<8, k<4)
    //   row(it,k) = h*128 + (t>>6) + 4*(it*4+k) ; cols c0..c0+3, c0=(t&63)*4
    const int w = t >> 6;
    const int c0 = (t & 63) << 2;

    float sum_p = 0.f, sum_pg = 0.f;
    int anyg = 0;
    unsigned rowbits = 0u;                        // bit n=it*4+k
    unsigned cb0 = 0, cb1 = 0, cb2 = 0, cb3 = 0;  // per-column presence
#pragma unroll
    for (int it = 0; it < 8; ++it) {
        if (it < 7) {  // issue next iteration's loads before consuming current
#pragma unroll
            for (int k = 0; k < 4; ++k) {
                const int off = ((it + 1) << 10) + (k << 8) + t;
                Pn[k] = __builtin_nontemporal_load(yp4 + off);
                Gn[k] = __builtin_nontemporal_load(yg4 + off);
            }
        }
#pragma unroll
        for (int k = 0; k < 4; ++k) {
            const f32x4 p = Pc[k], g = Gc[k];
            sum_p  += (p[0] + p[1]) + (p[2] + p[3]);
            sum_pg += p[0] * g[0] + p[1] * g[1] + p[2] * g[2] + p[3] * g[3];
            anyg |= (g[0] > 0.f) | (g[1] > 0.f) | (g[2] > 0.f) | (g[3] > 0.f);
            const unsigned bx = p[0] > 0.5f, by = p[1] > 0.5f,
                           bz = p[2] > 0.5f, bw = p[3] > 0.5f;
            rowbits |= (bx | by | bz | bw) << (it * 4 + k);
            cb0 |= bx; cb1 |= by; cb2 |= bz; cb3 |= bw;
        }
#pragma unroll
        for (int k = 0; k < 4; ++k) { Pc[k] = Pn[k]; Gc[k] = Gn[k]; }
    }

    // Collapse to per-thread box candidates.
    int minr = 0x7FFFFFFF, maxr = -1, minc = 0x7FFFFFFF, maxc = -1;
    if (rowbits) {
        minr = h * 128 + w + 4 * __builtin_ctz(rowbits);
        maxr = h * 128 + w + 4 * (31 - __builtin_clz(rowbits));
        const unsigned colbits = cb0 | (cb1 << 1) | (cb2 << 2) | (cb3 << 3);
        minc = c0 + __builtin_ctz(colbits);
        maxc = c0 + (31 - __builtin_clz(colbits));
    }

    // Wave reduce, then LDS across 4 waves, then one set of global atomics.
    const int wave = t >> 6, lane = t & 63;
    const float wsp = wave_sum(sum_p);
    const float wspg = wave_sum(sum_pg);
    const int wanyg = __any(anyg);
    const int wminr = wave_min(minr), wmaxr = wave_max(maxr);
    const int wminc = wave_min(minc), wmaxc = wave_max(maxc);

    __shared__ float sh_p[4], sh_pg[4];
    __shared__ int sh_a[4], sh_minr[4], sh_maxr[4], sh_minc[4], sh_maxc[4];
    if (lane == 0) {
        sh_p[wave] = wsp; sh_pg[wave] = wspg; sh_a[wave] = wanyg;
        sh_minr[wave] = wminr; sh_maxr[wave] = wmaxr;
        sh_minc[wave] = wminc; sh_maxc[wave] = wmaxc;
    }
    __syncthreads();
    if (t == 0) {
        float sp = 0.f, spg = 0.f;
        int a = 0, mnr = 0x7FFFFFFF, mxr = -1, mnc = 0x7FFFFFFF, mxc = -1;
#pragma unroll
        for (int i = 0; i < 4; ++i) {
            sp += sh_p[i]; spg += sh_pg[i]; a |= sh_a[i];
            mnr = min(mnr, sh_minr[i]); mxr = max(mxr, sh_maxr[i]);
            mnc = min(mnc, sh_minc[i]); mxc = max(mxc, sh_maxc[i]);
        }
        atomicAdd((float*)&rec[0], sp);
        atomicAdd((float*)&rec[1], spg);
        if (a) atomicOr(&rec[2], 1u);
        if (mxr >= 0) {   // this half saw blob pixels
            atomicMin((int*)&rec[3], mnr);
            atomicMax((int*)&rec[4], mxr);
            atomicMin((int*)&rec[5], mnc);
            atomicMax((int*)&rec[6], mxc);
        }
    }
}

// Pass 2: one wave per sample. Box math (redundant on all lanes) + tiny
// mask-box sum over Yp + ratio.
__global__ __launch_bounds__(64) void pass2_kernel(
    const float* __restrict__ Yp, const unsigned* __restrict__ recs,
    float* __restrict__ ratios) {
    const int b = blockIdx.x;
    const int lane = threadIdx.x;
    const unsigned* rec = recs + b * REC_WORDS;
    const float* yp = Yp + (size_t)b * L * L;

    const float sum_p  = ((const float*)rec)[0];
    const float sum_pg = ((const float*)rec)[1];
    const unsigned anyg = rec[2];
    const int minr = (int)rec[3], maxr = (int)rec[4];
    const int minc = (int)rec[5], maxc = (int)rec[6];

    // Faithful to reference (incl. the row/col swap and Python floor division).
    const bool any_r = maxr >= 0, any_c = maxc >= 0;
    const int left  = any_r ? minr : 0;
    const int right = any_r ? (L - 1 - maxr) : 0;
    const int up    = any_c ? minc : 0;
    const int down  = any_c ? (L - 1 - maxc) : 0;
    const int x_r = (right - left) >> 1;   // arithmetic shift = floor div
    const int y_r = (down - up) >> 1;
    const float gt0 = (float)(left + x_r); // compared against COLUMN coord
    const float gt1 = (float)(up + y_r);   // compared against ROW coord

    float positive;
    if (anyg) {
        positive = sum_pg;
    } else if (x_r == 0 || y_r == 0) {
        positive = 0.f;  // generated mask provably empty (inf/nan -> h not > 0.1)
    } else {
        const float inv_xr = 1.f / (float)x_r;
        const float inv_yr = 1.f / (float)y_r;
        // mask needs d0^4+d1^4 < ln(10)*4/9 => |d| <= 1.0059 ; pad a bit
        const float mx = fabsf((float)x_r) * 1.02f + 1.f;
        const float my = fabsf((float)y_r) * 1.02f + 1.f;
        const int cl = max(0, (int)floorf(gt0 - mx));
        const int ch = min(L - 1, (int)ceilf(gt0 + mx));
        const int rl = max(0, (int)floorf(gt1 - my));
        const int rh = min(L - 1, (int)ceilf(gt1 + my));
        const int W = ch - cl + 1, H = rh - rl + 1;
        float pos = 0.f;
        for (int idx = lane; idx < W * H; idx += 64) {
            const int r = rl + idx / W;
            const int c = cl + idx % W;
            float d0 = ((float)c - gt0) * inv_xr;
            float d1 = ((float)r - gt1) * inv_yr;
            d0 *= d0; d0 *= d0;    // d0^4
            d1 *= d1; d1 *= d1;    // d1^4
            const float h = __expf(-2.25f * (d0 + d1));  // exp(-h'/(2/3)^2)
            if (h > 0.1f) pos += yp[r * L + c];
        }
        positive = wave_sum(pos);  // valid in lane 0
    }
    if (lane == 0) ratios[b] = (sum_p - positive) / (positive + EPS);
}

__global__ __launch_bounds__(256) void finalize_kernel(
    const float* __restrict__ ratios, float* __restrict__ out, int B) {
    float v = 0.f;
    for (int i = threadIdx.x; i < B; i += 256) v += ratios[i];
    v = wave_sum(v);
    __shared__ float part[4];
    const int wave = threadIdx.x >> 6, lane = threadIdx.x & 63;
    if (lane == 0) part[wave] = v;
    __syncthreads();
    if (threadIdx.x == 0) {
        const float total = part[0] + part[1] + part[2] + part[3];
        out[0] = (total == 0.f) ? 0.f : logf(total) / (float)B;
    }
}

extern "C" void kernel_launch(void* const* d_in, const int* in_sizes, int n_in,
                              void* d_out, int out_size, void* d_ws, size_t ws_size,
                              hipStream_t stream) {
    const float* Yp = (const float*)d_in[0];
    const float* Yg = (const float*)d_in[1];
    const int B = in_sizes[0] / (L * L);
    unsigned* recs = (unsigned*)d_ws;                    // B*REC_WORDS u32
    float* ratios = (float*)((char*)d_ws + (size_t)B * REC_WORDS * 4);
    const int nz = B * REC_WORDS;
    init_kernel<<<(nz + 255) / 256, 256, 0, stream>>>(recs, nz);
    pass1_kernel<<<B * 2, 256, 0, stream>>>(Yp, Yg, recs);
    pass2_kernel<<<B, 64, 0, stream>>>(Yp, recs, ratios);
    finalize_kernel<<<1, 256, 0, stream>>>(ratios, (float*)d_out, B);
}

// Round 7
// 261.352 us; speedup vs baseline: 1.3038x; 1.0053x over previous
//
#include <hip/hip_runtime.h>
#include <math.h>

constexpr int L = 256;
constexpr float EPS = 1e-6f;
constexpr int REC_WORDS = 8;  // per-BLOCK record (u32 words)

// Per-block record (u32 words), plain-stored by each pass1 block (no init, no
// atomics): [0]=sum_p(f32) [1]=sum_pg(f32) [2]=anyg
// [3]=minr(i32, INT_MAX if none) [4]=maxr(i32, -1 if none)
// [5]=minc [6]=maxc [7]=pad.  Block blk = b*2+h owns recs[blk].

typedef float f32x4 __attribute__((ext_vector_type(4)));

__device__ inline float wave_sum(float v) {
#pragma unroll
    for (int off = 32; off > 0; off >>= 1) v += __shfl_down(v, off, 64);
    return v;
}
__device__ inline int wave_min(int v) {
#pragma unroll
    for (int off = 32; off > 0; off >>= 1) v = min(v, __shfl_down(v, off, 64));
    return v;
}
__device__ inline int wave_max(int v) {
#pragma unroll
    for (int off = 32; off > 0; off >>= 1) v = max(v, __shfl_down(v, off, 64));
    return v;
}

// Pass 1: grid = B*2 blocks of 256 threads. Each block streams a contiguous
// 128-row half of one sample (128 KB per array) as one software-pipelined
// load stream: 4+4 float4 register double-buffer, next iteration's loads in
// flight while current is consumed. Epilogue: plain-store a 32 B record.
__global__ __launch_bounds__(256) void pass1_kernel(
    const float* __restrict__ Yp, const float* __restrict__ Yg,
    unsigned* __restrict__ recs) {
    const int b = blockIdx.x >> 1;   // sample
    const int h = blockIdx.x & 1;    // 128-row half
    const int t = threadIdx.x;
    const f32x4* yp4 = (const f32x4*)(Yp + (size_t)b * L * L) + h * 8192;
    const f32x4* yg4 = (const f32x4*)(Yg + (size_t)b * L * L) + h * 8192;
    unsigned* rec = recs + blockIdx.x * REC_WORDS;

    // Prologue: load iteration 0's 8 float4.
    f32x4 Pc[4], Gc[4], Pn[4], Gn[4];
#pragma unroll
    for (int k = 0; k < 4; ++k) {
        Pc[k] = __builtin_nontemporal_load(yp4 + (k << 8) + t);
        Gc[k] = __builtin_nontemporal_load(yg4 + (k << 8) + t);
    }

    // Per-thread geometry is data-independent:
    //   float4 idx j = it*1024 + k*256 + t  (it<8, k<4)
    //   row(it,k) = h*128 + (t>>6) + 16*it + 4*k ; cols c0..c0+3, c0=(t&63)*4
    const int w = t >> 6;
    const int c0 = (t & 63) << 2;

    float sum_p = 0.f, sum_pg = 0.f;
    int anyg = 0;
    unsigned rowbits = 0u;                        // bit n=it*4+k -> row off 4n
    unsigned cb0 = 0, cb1 = 0, cb2 = 0, cb3 = 0;  // per-column presence
#pragma unroll
    for (int it = 0; it < 8; ++it) {
        if (it < 7) {  // issue next iteration's loads before consuming current
#pragma unroll
            for (int k = 0; k < 4; ++k) {
                const int off = ((it + 1) << 10) + (k << 8) + t;
                Pn[k] = __builtin_nontemporal_load(yp4 + off);
                Gn[k] = __builtin_nontemporal_load(yg4 + off);
            }
        }
#pragma unroll
        for (int k = 0; k < 4; ++k) {
            const f32x4 p = Pc[k], g = Gc[k];
            sum_p  += (p[0] + p[1]) + (p[2] + p[3]);
            sum_pg += p[0] * g[0] + p[1] * g[1] + p[2] * g[2] + p[3] * g[3];
            anyg |= (g[0] > 0.f) | (g[1] > 0.f) | (g[2] > 0.f) | (g[3] > 0.f);
            const unsigned bx = p[0] > 0.5f, by = p[1] > 0.5f,
                           bz = p[2] > 0.5f, bw = p[3] > 0.5f;
            rowbits |= (bx | by | bz | bw) << (it * 4 + k);
            cb0 |= bx; cb1 |= by; cb2 |= bz; cb3 |= bw;
        }
#pragma unroll
        for (int k = 0; k < 4; ++k) { Pc[k] = Pn[k]; Gc[k] = Gn[k]; }
    }

    // Collapse to per-thread box candidates.
    int minr = 0x7FFFFFFF, maxr = -1, minc = 0x7FFFFFFF, maxc = -1;
    if (rowbits) {
        minr = h * 128 + w + 4 * __builtin_ctz(rowbits);
        maxr = h * 128 + w + 4 * (31 - __builtin_clz(rowbits));
        const unsigned colbits = cb0 | (cb1 << 1) | (cb2 << 2) | (cb3 << 3);
        minc = c0 + __builtin_ctz(colbits);
        maxc = c0 + (31 - __builtin_clz(colbits));
    }

    // Wave reduce, LDS across 4 waves, then ONE plain 32 B record store.
    const int wave = t >> 6, lane = t & 63;
    const float wsp = wave_sum(sum_p);
    const float wspg = wave_sum(sum_pg);
    const int wanyg = __any(anyg);
    const int wminr = wave_min(minr), wmaxr = wave_max(maxr);
    const int wminc = wave_min(minc), wmaxc = wave_max(maxc);

    __shared__ float sh_p[4], sh_pg[4];
    __shared__ int sh_a[4], sh_minr[4], sh_maxr[4], sh_minc[4], sh_maxc[4];
    if (lane == 0) {
        sh_p[wave] = wsp; sh_pg[wave] = wspg; sh_a[wave] = wanyg;
        sh_minr[wave] = wminr; sh_maxr[wave] = wmaxr;
        sh_minc[wave] = wminc; sh_maxc[wave] = wmaxc;
    }
    __syncthreads();
    if (t == 0) {
        float sp = 0.f, spg = 0.f;
        int a = 0, mnr = 0x7FFFFFFF, mxr = -1, mnc = 0x7FFFFFFF, mxc = -1;
#pragma unroll
        for (int i = 0; i < 4; ++i) {
            sp += sh_p[i]; spg += sh_pg[i]; a |= sh_a[i];
            mnr = min(mnr, sh_minr[i]); mxr = max(mxr, sh_maxr[i]);
            mnc = min(mnc, sh_minc[i]); mxc = max(mxc, sh_maxc[i]);
        }
        ((float*)rec)[0] = sp;
        ((float*)rec)[1] = spg;
        rec[2] = (unsigned)a;
        ((int*)rec)[3] = mnr; ((int*)rec)[4] = mxr;
        ((int*)rec)[5] = mnc; ((int*)rec)[6] = mxc;
        rec[7] = 0u;
    }
}

// Pass 2: one wave per sample. Merge the two half-records, box math
// (redundant on all lanes) + tiny mask-box sum over Yp + ratio.
__global__ __launch_bounds__(64) void pass2_kernel(
    const float* __restrict__ Yp, const unsigned* __restrict__ recs,
    float* __restrict__ ratios) {
    const int b = blockIdx.x;
    const int lane = threadIdx.x;
    const unsigned* r0 = recs + (2 * b + 0) * REC_WORDS;
    const unsigned* r1 = recs + (2 * b + 1) * REC_WORDS;
    const float* yp = Yp + (size_t)b * L * L;

    const float sum_p  = ((const float*)r0)[0] + ((const float*)r1)[0];
    const float sum_pg = ((const float*)r0)[1] + ((const float*)r1)[1];
    const unsigned anyg = r0[2] | r1[2];
    const int minr = min((int)r0[3], (int)r1[3]);
    const int maxr = max((int)r0[4], (int)r1[4]);
    const int minc = min((int)r0[5], (int)r1[5]);
    const int maxc = max((int)r0[6], (int)r1[6]);

    // Faithful to reference (incl. the row/col swap and Python floor division).
    const bool any_r = maxr >= 0, any_c = maxc >= 0;
    const int left  = any_r ? minr : 0;
    const int right = any_r ? (L - 1 - maxr) : 0;
    const int up    = any_c ? minc : 0;
    const int down  = any_c ? (L - 1 - maxc) : 0;
    const int x_r = (right - left) >> 1;   // arithmetic shift = floor div
    const int y_r = (down - up) >> 1;
    const float gt0 = (float)(left + x_r); // compared against COLUMN coord
    const float gt1 = (float)(up + y_r);   // compared against ROW coord

    float positive;
    if (anyg) {
        positive = sum_pg;
    } else if (x_r == 0 || y_r == 0) {
        positive = 0.f;  // generated mask provably empty (inf/nan -> h not > 0.1)
    } else {
        const float inv_xr = 1.f / (float)x_r;
        const float inv_yr = 1.f / (float)y_r;
        // mask needs d0^4+d1^4 < ln(10)*4/9 => |d| <= 1.0059 ; pad a bit
        const float mx = fabsf((float)x_r) * 1.02f + 1.f;
        const float my = fabsf((float)y_r) * 1.02f + 1.f;
        const int cl = max(0, (int)floorf(gt0 - mx));
        const int ch = min(L - 1, (int)ceilf(gt0 + mx));
        const int rl = max(0, (int)floorf(gt1 - my));
        const int rh = min(L - 1, (int)ceilf(gt1 + my));
        const int W = ch - cl + 1, H = rh - rl + 1;
        float pos = 0.f;
        for (int idx = lane; idx < W * H; idx += 64) {
            const int r = rl + idx / W;
            const int c = cl + idx % W;
            float d0 = ((float)c - gt0) * inv_xr;
            float d1 = ((float)r - gt1) * inv_yr;
            d0 *= d0; d0 *= d0;    // d0^4
            d1 *= d1; d1 *= d1;    // d1^4
            const float h = __expf(-2.25f * (d0 + d1));  // exp(-h'/(2/3)^2)
            if (h > 0.1f) pos += yp[r * L + c];
        }
        positive = wave_sum(pos);  // valid in lane 0
    }
    if (lane == 0) ratios[b] = (sum_p - positive) / (positive + EPS);
}

__global__ __launch_bounds__(256) void finalize_kernel(
    const float* __restrict__ ratios, float* __restrict__ out, int B) {
    float v = 0.f;
    for (int i = threadIdx.x; i < B; i += 256) v += ratios[i];
    v = wave_sum(v);
    __shared__ float part[4];
    const int wave = threadIdx.x >> 6, lane = threadIdx.x & 63;
    if (lane == 0) part[wave] = v;
    __syncthreads();
    if (threadIdx.x == 0) {
        const float total = part[0] + part[1] + part[2] + part[3];
        out[0] = (total == 0.f) ? 0.f : logf(total) / (float)B;
    }
}

extern "C" void kernel_launch(void* const* d_in, const int* in_sizes, int n_in,
                              void* d_out, int out_size, void* d_ws, size_t ws_size,
                              hipStream_t stream) {
    const float* Yp = (const float*)d_in[0];
    const float* Yg = (const float*)d_in[1];
    const int B = in_sizes[0] / (L * L);
    unsigned* recs = (unsigned*)d_ws;                    // B*2*REC_WORDS u32
    float* ratios = (float*)((char*)d_ws + (size_t)B * 2 * REC_WORDS * 4);
    pass1_kernel<<<B * 2, 256, 0, stream>>>(Yp, Yg, recs);
    pass2_kernel<<<B, 64, 0, stream>>>(Yp, recs, ratios);
    finalize_kernel<<<1, 256, 0, stream>>>(ratios, (float*)d_out, B);
}